// Round 2
// baseline (698.911 us; speedup 1.0000x reference)
//
#include <hip/hip_runtime.h>

// MoE Transformer encoder layer, MI355X/gfx950.
// R5: grouped GEMM rebuilt as a counted-wait software pipeline.
//  - 256 threads / 4 waves, tile M=128 N=128 BK=32 (2x working blocks/CU).
//  - ALL staging via registers -> LDS: A 1-step ahead, B (fp32 weights,
//    cold-HBM stream) 2 steps ahead. Compiler emits exact counted vmcnt
//    for register loads, so nothing is ever drained to 0 in the loop.
//  - RAW s_barrier + hand lgkmcnt(0) (no __syncthreads vmcnt(0) drain):
//    prefetch loads stay in flight across barriers (T3/T4).
//  - Single-buffered LDS (publish happens after the compute barrier),
//    XOR chunk swizzles on both As and Bs (R3/R4-proven layouts).
//  - s_setprio(1) around MFMA cluster.

#define B_   2
#define N_   1024
#define D_   1024
#define H_   16
#define DH_  64
#define FF_  4096
#define E_   8
#define NTOK 2048

typedef __attribute__((ext_vector_type(8))) short short8;
typedef __attribute__((ext_vector_type(8))) unsigned short ushort8;
typedef __attribute__((ext_vector_type(4))) unsigned short ushort4v;
typedef __attribute__((ext_vector_type(4))) float f32x4;
typedef __attribute__((ext_vector_type(2))) unsigned int uint32x2;

__device__ inline unsigned short f2bf(float f) {
  unsigned u = __float_as_uint(f);
  u += 0x7FFFu + ((u >> 16) & 1u);   // round-to-nearest-even
  return (unsigned short)(u >> 16);
}

__device__ inline float gelu_tanh(float x) {
  float x3 = x * x * x;
  float t = tanhf(0.7978845608028654f * (x + 0.044715f * x3));
  return 0.5f * x * (1.0f + t);
}

// ---------------- gating: one wave per token, fp32 exact ----------------
__global__ __launch_bounds__(256) void gate_kernel(
    const float* __restrict__ X, const float* __restrict__ Wg,
    int* __restrict__ idx, float* __restrict__ gwv, int* __restrict__ cnt) {
  int t = blockIdx.x * 4 + (threadIdx.x >> 6);
  int lane = threadIdx.x & 63;
  const float* x = X + (size_t)t * D_;
  float acc[E_];
#pragma unroll
  for (int j = 0; j < E_; j++) acc[j] = 0.f;
#pragma unroll
  for (int i = 0; i < 16; i++) {
    int d = i * 64 + lane;
    float xv = x[d];
    const float4* w = (const float4*)(Wg + (size_t)d * E_);
    float4 w0 = w[0], w1 = w[1];
    acc[0] += xv * w0.x; acc[1] += xv * w0.y; acc[2] += xv * w0.z; acc[3] += xv * w0.w;
    acc[4] += xv * w1.x; acc[5] += xv * w1.y; acc[6] += xv * w1.z; acc[7] += xv * w1.w;
  }
#pragma unroll
  for (int o = 1; o < 64; o <<= 1) {
#pragma unroll
    for (int j = 0; j < E_; j++) acc[j] += __shfl_xor(acc[j], o, 64);
  }
  float m = acc[0]; int bi = 0;
#pragma unroll
  for (int j = 1; j < E_; j++) { if (acc[j] > m) { m = acc[j]; bi = j; } }
  float den = 0.f;
#pragma unroll
  for (int j = 0; j < E_; j++) den += expf(acc[j] - m);
  float gw = expf(acc[bi] - m) / den;
  if (lane == 0) { idx[t] = bi; gwv[t] = gw; atomicAdd(&cnt[bi], 1); }
}

// ---------------- routing: single block builds per-expert lists ----------------
__global__ __launch_bounds__(256) void route_kernel(
    const int* __restrict__ idx, const int* __restrict__ cnt,
    int* __restrict__ off, int* __restrict__ perm, int ntok) {
  __shared__ int loff[E_ + 1];
  __shared__ int lfill[E_];
  if (threadIdx.x == 0) {
    int s = 0;
    for (int e = 0; e < E_; e++) { loff[e] = s; s += cnt[e]; }
    loff[E_] = s;
  }
  if (threadIdx.x < E_) lfill[threadIdx.x] = 0;
  __syncthreads();
  for (int t = (int)threadIdx.x; t < ntok; t += 256) {
    int e = idx[t];
    int p = atomicAdd(&lfill[e], 1);
    perm[loff[e] + p] = t;
  }
  if (threadIdx.x < E_ + 1) off[threadIdx.x] = loff[threadIdx.x];
}

// ---------------- fp32 -> bf16 bulk cast ----------------
__global__ __launch_bounds__(256) void cast_bf16_kernel(
    const float* __restrict__ in, unsigned short* __restrict__ out) {
  size_t i = ((size_t)blockIdx.x * 256 + threadIdx.x) * 8;
  float4 v0 = *(const float4*)(in + i);
  float4 v1 = *(const float4*)(in + i + 4);
  ushort8 o;
  o[0] = f2bf(v0.x); o[1] = f2bf(v0.y); o[2] = f2bf(v0.z); o[3] = f2bf(v0.w);
  o[4] = f2bf(v1.x); o[5] = f2bf(v1.y); o[6] = f2bf(v1.z); o[7] = f2bf(v1.w);
  *(ushort8*)(out + i) = o;
}

// ---------------- grouped MoE GEMM, counted-wait pipeline ----------------
// part[kc][t][n] = A[t]·W[e][:,n] over K-chunk kc. Tiles: M=128, N=128, BK=32.
// 256 threads = 4 waves (2m x 2n), each wave 64m x 64n (4x4 16x16x32 frags).
// A bf16 [tok][K]: thread -> row tid>>1, two 16B chunks at (tid&1)*2; LDS
//   chunk c holds source chunk c^((row>>1)&3).
// W fp32 [E][K][N]: thread -> 4 k-rows (tid&7)*4 x 4 n (tid>>3)*4; cast+
//   transposed to Bs, k-block b at LDS block b^((n>>2)&3).
// Loop: publish(t) -> issue A(t+1),B(t+2) -> lgkmcnt(0); s_barrier ->
//   compute(t) -> s_barrier.  No vmcnt drain anywhere in the loop.
template <int KS>
__global__ __launch_bounds__(256, 3) void gemm_kernel(
    const unsigned short* __restrict__ A, int ldA,
    const float* __restrict__ W,
    const int* __restrict__ perm, const int* __restrict__ off,
    float* __restrict__ part, int K, int N) {
  __shared__ __align__(16) unsigned short As[128][32];
  __shared__ __align__(16) unsigned short Bs[128][40];
  __shared__ int toks[128];

  int e = blockIdx.y;
  int base = off[e];
  int cnt = off[e + 1] - base;
  int mt = blockIdx.z / KS;
  int kc = blockIdx.z % KS;
  int m0 = mt * 128;
  if (m0 >= cnt) return;
  int rows_valid = min(128, cnt - m0);
  int tid = threadIdx.x;
  if (tid < 128) {
    int r = (tid < rows_valid) ? tid : (rows_valid - 1);
    toks[tid] = perm[base + m0 + r];
  }
  int nb = blockIdx.x * 128;
  int lane = tid & 63, wave = tid >> 6;
  int wm = (wave & 1) * 64, wn = (wave >> 1) * 64;
  int lr = lane & 15, lg = lane >> 4;
  int aswz = (lg ^ ((lr >> 1) & 3)) << 3;
  int bswz = (lg ^ ((lr >> 2) & 3)) << 3;

  f32x4 acc[4][4];
#pragma unroll
  for (int m = 0; m < 4; m++)
#pragma unroll
    for (int n = 0; n < 4; n++) acc[m][n] = (f32x4){0.f, 0.f, 0.f, 0.f};

  // staging geometry
  int arow = tid >> 1;
  int aj0 = (tid & 1) * 2;           // first source 16B chunk
  int as_ = (arow >> 1) & 3;         // A row swizzle
  int k4 = (tid & 7) * 4, n0 = (tid >> 3) * 4;

  int KL = K / KS, kbeg = kc * KL;
  int nt = KL / 32;
  __syncthreads();   // toks visible

  const unsigned short* abase = A + (size_t)toks[arow] * ldA + aj0 * 8;
  const float* wbase = W + ((size_t)e * K + k4) * N + nb + n0;

  ushort8 aR0, aR1;
  f32x4 bA0, bA1, bA2, bA3, bB0, bB1, bB2, bB3;

#define LOAD_A(KK) {                                                      \
    const unsigned short* ap = abase + (KK);                              \
    aR0 = *(const ushort8*)ap;                                            \
    aR1 = *(const ushort8*)(ap + 8); }

#define LOAD_B(KK, R0, R1, R2, R3) {                                      \
    const float* wp = wbase + (size_t)(KK) * N;                           \
    R0 = *(const f32x4*)wp;                                               \
    R1 = *(const f32x4*)(wp + N);                                         \
    R2 = *(const f32x4*)(wp + 2 * N);                                     \
    R3 = *(const f32x4*)(wp + 3 * N); }

#define PUBLISH(R0, R1, R2, R3) {                                         \
    *(ushort8*)&As[arow][(aj0 ^ as_) << 3] = aR0;                         \
    *(ushort8*)&As[arow][((aj0 + 1) ^ as_) << 3] = aR1;                   \
    _Pragma("unroll")                                                     \
    for (int j = 0; j < 4; j++) {                                         \
      int n = n0 + j;                                                     \
      int bb = (((k4 >> 3) ^ ((n >> 2) & 3)) << 3) | (k4 & 7);            \
      unsigned lo = (unsigned)f2bf(R0[j]) | ((unsigned)f2bf(R1[j]) << 16);\
      unsigned hi = (unsigned)f2bf(R2[j]) | ((unsigned)f2bf(R3[j]) << 16);\
      *(uint32x2*)&Bs[n][bb] = (uint32x2){lo, hi};                        \
    } }

#define COMPUTE() {                                                       \
    short8 av[4], bv[4];                                                  \
    _Pragma("unroll")                                                     \
    for (int m = 0; m < 4; m++)                                           \
      av[m] = *(const short8*)&As[wm + m * 16 + lr][aswz];                \
    _Pragma("unroll")                                                     \
    for (int n = 0; n < 4; n++)                                           \
      bv[n] = *(const short8*)&Bs[wn + n * 16 + lr][bswz];                \
    __builtin_amdgcn_s_setprio(1);                                        \
    _Pragma("unroll")                                                     \
    for (int n = 0; n < 4; n++)                                           \
      _Pragma("unroll")                                                   \
      for (int m = 0; m < 4; m++)                                         \
        acc[m][n] = __builtin_amdgcn_mfma_f32_16x16x32_bf16(              \
            av[m], bv[n], acc[m][n], 0, 0, 0);                            \
    __builtin_amdgcn_s_setprio(0); }

  // prologue: A(0), B(0), B(1)
  LOAD_A(kbeg);
  LOAD_B(kbeg, bA0, bA1, bA2, bA3);
  if (nt > 1) LOAD_B(kbeg + 32, bB0, bB1, bB2, bB3);

  for (int t = 0; t < nt; t += 2) {
    int k0 = kbeg + t * 32;
    // ---- even step t ----
    PUBLISH(bA0, bA1, bA2, bA3);
    if (t + 1 < nt) LOAD_A(k0 + 32);
    if (t + 2 < nt) LOAD_B(k0 + 64, bA0, bA1, bA2, bA3);
    asm volatile("s_waitcnt lgkmcnt(0)" ::: "memory");
    __builtin_amdgcn_s_barrier();
    COMPUTE();
    __builtin_amdgcn_s_barrier();
    // ---- odd step t+1 ----
    if (t + 1 < nt) {
      PUBLISH(bB0, bB1, bB2, bB3);
      if (t + 2 < nt) LOAD_A(k0 + 64);
      if (t + 3 < nt) LOAD_B(k0 + 96, bB0, bB1, bB2, bB3);
      asm volatile("s_waitcnt lgkmcnt(0)" ::: "memory");
      __builtin_amdgcn_s_barrier();
      COMPUTE();
      __builtin_amdgcn_s_barrier();
    }
  }
#undef LOAD_A
#undef LOAD_B
#undef PUBLISH
#undef COMPUTE

  float* pr = part + (size_t)kc * ((size_t)NTOK * N);
#pragma unroll
  for (int n = 0; n < 4; n++) {
    int col = nb + wn + n * 16 + lr;
#pragma unroll
    for (int m = 0; m < 4; m++) {
#pragma unroll
      for (int reg = 0; reg < 4; reg++) {
        int r = wm + m * 16 + lg * 4 + reg;
        if (r < rows_valid)
          pr[(size_t)toks[r] * N + col] = acc[m][n][reg];
      }
    }
  }
}

// ---------------- reduce partials + bias + gate (+gelu), cast ----------------
template <int KS, bool GELU, bool OBF16>
__global__ __launch_bounds__(256) void reduce_kernel(
    const float* __restrict__ part, const float* __restrict__ bias,
    const float* __restrict__ gwv, const int* __restrict__ idx,
    void* __restrict__ out, int N) {
  int t = blockIdx.y;
  int n = (blockIdx.x * 256 + threadIdx.x) * 4;
  int e = idx[t];
  float gw = gwv[t];
  const float* p = part + (size_t)t * N + n;
  float4 a = *(const float4*)p;
#pragma unroll
  for (int k = 1; k < KS; k++) {
    float4 q = *(const float4*)(p + (size_t)k * NTOK * N);
    a.x += q.x; a.y += q.y; a.z += q.z; a.w += q.w;
  }
  float4 bv = *(const float4*)(bias + (size_t)e * N + n);
  a.x = (a.x + bv.x) * gw; a.y = (a.y + bv.y) * gw;
  a.z = (a.z + bv.z) * gw; a.w = (a.w + bv.w) * gw;
  if constexpr (GELU) {
    a.x = gelu_tanh(a.x); a.y = gelu_tanh(a.y);
    a.z = gelu_tanh(a.z); a.w = gelu_tanh(a.w);
  }
  if constexpr (OBF16) {
    ushort4v o;
    o[0] = f2bf(a.x); o[1] = f2bf(a.y); o[2] = f2bf(a.z); o[3] = f2bf(a.w);
    *(ushort4v*)((unsigned short*)out + (size_t)t * N + n) = o;
  } else {
    *(float4*)((float*)out + (size_t)t * N + n) = a;
  }
}

// ---------------- V transpose per (b,h) ----------------
__global__ __launch_bounds__(256) void vtrans_kernel(
    const unsigned short* __restrict__ qkv, unsigned short* __restrict__ vT) {
  __shared__ __align__(16) unsigned short T[64][72];
  int bh = blockIdx.x;
  int b = bh >> 4, h = bh & 15;
  int tile = blockIdx.y;
  int tid = threadIdx.x;
  {
    int tk = tid >> 2, dof = (tid & 3) * 16;
    const unsigned short* p =
        qkv + ((size_t)(b * N_ + tile * 64 + tk)) * 3072 + 2048 + h * 64 + dof;
    *(ushort8*)&T[tk][dof] = *(const ushort8*)p;
    *(ushort8*)&T[tk][dof + 8] = *(const ushort8*)(p + 8);
  }
  __syncthreads();
  {
    int dh = tid >> 2, tof = (tid & 3) * 16;
    ushort8 o0, o1;
#pragma unroll
    for (int i = 0; i < 8; i++) o0[i] = T[tof + i][dh];
#pragma unroll
    for (int i = 0; i < 8; i++) o1[i] = T[tof + 8 + i][dh];
    unsigned short* q = vT + ((size_t)bh * 64 + dh) * N_ + tile * 64 + tof;
    *(ushort8*)q = o0;
    *(ushort8*)(q + 8) = o1;
  }
}

// ---------------- flash attention ----------------
__global__ __launch_bounds__(256) void attn_kernel(
    const unsigned short* __restrict__ qkv, const unsigned short* __restrict__ vT,
    const unsigned char* __restrict__ kpm, unsigned short* __restrict__ ctx) {
  __shared__ __align__(16) unsigned short Qs[64][72];
  __shared__ __align__(16) unsigned short Ks[64][72];
  __shared__ __align__(16) unsigned short Vs[64][72];
  __shared__ __align__(16) unsigned short Ps[4][16][72];
  __shared__ float maskf[64];
  int qt = blockIdx.x, bh = blockIdx.y;
  int b = bh >> 4, h = bh & 15;
  int tid = threadIdx.x, lane = tid & 63, wave = tid >> 6;
  int lr = lane & 15, lg = lane >> 4;
  {
    int r = tid >> 2, dof = (tid & 3) * 16;
    const unsigned short* p = qkv + ((size_t)(b * N_ + qt * 64 + r)) * 3072 + h * 64 + dof;
    *(ushort8*)&Qs[r][dof] = *(const ushort8*)p;
    *(ushort8*)&Qs[r][dof + 8] = *(const ushort8*)(p + 8);
  }
  __syncthreads();
  short8 aq[2];
  aq[0] = *(const short8*)&Qs[wave * 16 + lr][lg * 8];
  aq[1] = *(const short8*)&Qs[wave * 16 + lr][32 + lg * 8];
  f32x4 O[4];
  float mrun[4], lrun[4];
#pragma unroll
  for (int r = 0; r < 4; r++) { mrun[r] = -1e30f; lrun[r] = 0.f; O[r] = (f32x4){0.f, 0.f, 0.f, 0.f}; }

  for (int kt = 0; kt < 16; kt++) {
    __syncthreads();
    {
      int r = tid >> 2, dof = (tid & 3) * 16;
      const unsigned short* p =
          qkv + ((size_t)(b * N_ + kt * 64 + r)) * 3072 + 1024 + h * 64 + dof;
      *(ushort8*)&Ks[r][dof] = *(const ushort8*)p;
      *(ushort8*)&Ks[r][dof + 8] = *(const ushort8*)(p + 8);
      const unsigned short* pv = vT + ((size_t)bh * 64 + r) * N_ + kt * 64 + dof;
      *(ushort8*)&Vs[r][dof] = *(const ushort8*)pv;
      *(ushort8*)&Vs[r][dof + 8] = *(const ushort8*)(pv + 8);
      if (tid < 64) maskf[tid] = kpm[b * N_ + kt * 64 + tid] ? -10000.f : 0.f;
    }
    __syncthreads();
    f32x4 S[4];
#pragma unroll
    for (int n = 0; n < 4; n++) {
      f32x4 s = (f32x4){0.f, 0.f, 0.f, 0.f};
#pragma unroll
      for (int ks = 0; ks < 2; ks++) {
        short8 bk = *(const short8*)&Ks[n * 16 + lr][ks * 32 + lg * 8];
        s = __builtin_amdgcn_mfma_f32_16x16x32_bf16(aq[ks], bk, s, 0, 0, 0);
      }
      float mv = maskf[n * 16 + lr];
#pragma unroll
      for (int r = 0; r < 4; r++) s[r] = s[r] * 0.125f + mv;
      S[n] = s;
    }
    float cur[4];
#pragma unroll
    for (int r = 0; r < 4; r++)
      cur[r] = fmaxf(fmaxf(S[0][r], S[1][r]), fmaxf(S[2][r], S[3][r]));
#pragma unroll
    for (int o = 1; o < 16; o <<= 1) {
#pragma unroll
      for (int r = 0; r < 4; r++) cur[r] = fmaxf(cur[r], __shfl_xor(cur[r], o, 64));
    }
    float alpha[4], rsum[4];
#pragma unroll
    for (int r = 0; r < 4; r++) {
      float mn = fmaxf(mrun[r], cur[r]);
      alpha[r] = expf(mrun[r] - mn);
      mrun[r] = mn;
      rsum[r] = 0.f;
    }
#pragma unroll
    for (int n = 0; n < 4; n++) {
#pragma unroll
      for (int r = 0; r < 4; r++) {
        S[n][r] = expf(S[n][r] - mrun[r]);
        rsum[r] += S[n][r];
      }
    }
#pragma unroll
    for (int o = 1; o < 16; o <<= 1) {
#pragma unroll
      for (int r = 0; r < 4; r++) rsum[r] += __shfl_xor(rsum[r], o, 64);
    }
#pragma unroll
    for (int r = 0; r < 4; r++) lrun[r] = lrun[r] * alpha[r] + rsum[r];
#pragma unroll
    for (int d = 0; d < 4; d++)
#pragma unroll
      for (int r = 0; r < 4; r++) O[d][r] *= alpha[r];
#pragma unroll
    for (int n = 0; n < 4; n++)
#pragma unroll
      for (int r = 0; r < 4; r++) Ps[wave][lg * 4 + r][n * 16 + lr] = f2bf(S[n][r]);
    short8 pf[2];
    pf[0] = *(const short8*)&Ps[wave][lr][lg * 8];
    pf[1] = *(const short8*)&Ps[wave][lr][32 + lg * 8];
#pragma unroll
    for (int d = 0; d < 4; d++) {
#pragma unroll
      for (int ks = 0; ks < 2; ks++) {
        short8 bv = *(const short8*)&Vs[d * 16 + lr][ks * 32 + lg * 8];
        O[d] = __builtin_amdgcn_mfma_f32_16x16x32_bf16(pf[ks], bv, O[d], 0, 0, 0);
      }
    }
  }
#pragma unroll
  for (int r = 0; r < 4; r++) lrun[r] = 1.f / lrun[r];
#pragma unroll
  for (int d = 0; d < 4; d++) {
#pragma unroll
    for (int r = 0; r < 4; r++) {
      int q = qt * 64 + wave * 16 + lg * 4 + r;
      int dh = d * 16 + lr;
      ctx[((size_t)(b * N_ + q)) * D_ + h * DH_ + dh] = f2bf(O[d][r] * lrun[r]);
    }
  }
}

// ---------------- fused: out = LN(res + (Σ part + bias)·gw) [+bf16 copy] ----------------
template <int KS, bool WBF>
__global__ __launch_bounds__(256) void ln_reduce_kernel(
    const float* __restrict__ res, const float* __restrict__ part,
    const float* __restrict__ bias, const float* __restrict__ gwv,
    const int* __restrict__ idx,
    const float* __restrict__ S, const float* __restrict__ Bi,
    float* __restrict__ O, unsigned short* __restrict__ Obf) {
  int t = blockIdx.x, tid = threadIdx.x;
  int e = idx[t];
  float gw = gwv[t];
  const float* p = part + (size_t)t * D_ + tid * 4;
  float4 a = *(const float4*)p;
#pragma unroll
  for (int k = 1; k < KS; k++) {
    float4 q = *(const float4*)(p + (size_t)k * NTOK * D_);
    a.x += q.x; a.y += q.y; a.z += q.z; a.w += q.w;
  }
  float4 bv4 = *(const float4*)(bias + (size_t)e * D_ + tid * 4);
  float4 vr = ((const float4*)(res + (size_t)t * D_))[tid];
  float4 v;
  v.x = vr.x + (a.x + bv4.x) * gw;
  v.y = vr.y + (a.y + bv4.y) * gw;
  v.z = vr.z + (a.z + bv4.z) * gw;
  v.w = vr.w + (a.w + bv4.w) * gw;
  float s = v.x + v.y + v.z + v.w;
  float sq = v.x * v.x + v.y * v.y + v.z * v.z + v.w * v.w;
#pragma unroll
  for (int o = 1; o < 64; o <<= 1) {
    s += __shfl_xor(s, o, 64);
    sq += __shfl_xor(sq, o, 64);
  }
  __shared__ float ss[4], ssq[4];
  int wave = tid >> 6, lane = tid & 63;
  if (lane == 0) { ss[wave] = s; ssq[wave] = sq; }
  __syncthreads();
  float ts = ss[0] + ss[1] + ss[2] + ss[3];
  float tsq = ssq[0] + ssq[1] + ssq[2] + ssq[3];
  float mean = ts * (1.f / D_);
  float var = tsq * (1.f / D_) - mean * mean;
  float rs = rsqrtf(var + 1e-5f);
  float4 sv = ((const float4*)S)[tid];
  float4 bi = ((const float4*)Bi)[tid];
  float4 o;
  o.x = (v.x - mean) * rs * sv.x + bi.x;
  o.y = (v.y - mean) * rs * sv.y + bi.y;
  o.z = (v.z - mean) * rs * sv.z + bi.z;
  o.w = (v.w - mean) * rs * sv.w + bi.w;
  ((float4*)(O + (size_t)t * D_))[tid] = o;
  if constexpr (WBF) {
    ushort4v ob;
    ob[0] = f2bf(o.x); ob[1] = f2bf(o.y); ob[2] = f2bf(o.z); ob[3] = f2bf(o.w);
    *(ushort4v*)(Obf + (size_t)t * D_ + tid * 4) = ob;
  }
}

extern "C" void kernel_launch(void* const* d_in, const int* in_sizes, int n_in,
                              void* d_out, int out_size, void* d_ws, size_t ws_size,
                              hipStream_t stream) {
  (void)in_sizes; (void)n_in; (void)out_size; (void)ws_size;
  const float* src     = (const float*)d_in[0];
  const unsigned char* kpm = (const unsigned char*)d_in[1];
  const float* Wg_attn = (const float*)d_in[2];
  const float* Wqkv    = (const float*)d_in[3];
  const float* bqkv    = (const float*)d_in[4];
  const float* Wo      = (const float*)d_in[5];
  const float* bo      = (const float*)d_in[6];
  const float* Wg_ffn  = (const float*)d_in[7];
  const float* W1      = (const float*)d_in[8];
  const float* b1      = (const float*)d_in[9];
  const float* W2      = (const float*)d_in[10];
  const float* b2      = (const float*)d_in[11];
  const float* ln1_s   = (const float*)d_in[12];
  const float* ln1_b   = (const float*)d_in[13];
  const float* ln2_s   = (const float*)d_in[14];
  const float* ln2_b   = (const float*)d_in[15];
  float* out = (float*)d_out;

  char* ws = (char*)d_ws;
  size_t o = 0;
  auto alloc = [&](size_t bytes) -> void* {
    void* p = ws + o;
    o += (bytes + 255) & ~(size_t)255;
    return p;
  };
  int* meta = (int*)alloc(256);
  int* cnt1 = meta;
  int* off1 = meta + 8;
  int* cnt2 = meta + 17;
  int* off2 = meta + 25;
  int* idx1 = (int*)alloc(NTOK * 4);
  float* gw1 = (float*)alloc(NTOK * 4);
  int* perm1 = (int*)alloc(NTOK * 4);
  int* idx2 = (int*)alloc(NTOK * 4);
  float* gw2 = (float*)alloc(NTOK * 4);
  int* perm2 = (int*)alloc(NTOK * 4);
  unsigned short* qkvb = (unsigned short*)alloc((size_t)NTOK * 3072 * 2);   // 12.6 MB
  unsigned short* vT = (unsigned short*)alloc((size_t)32 * 64 * N_ * 2);    // 4.2 MB
  unsigned short* hbuf = qkvb;  // h[2048][4096] bf16 reuses qkv+vT (16.78 MB)
  unsigned short* ctx = (unsigned short*)alloc((size_t)NTOK * D_ * 2);      // 4.2 MB
  // ctx buffer triple-duty (all lifetimes disjoint on the stream):
  //   [cast .. QKV gemm]      src_bf (bf16 src)
  //   [attn .. Wo gemm]       ctx (attention output)
  //   [ln_reduce1 .. W1 gemm] x_bf (bf16 x)
  unsigned short* src_bf = ctx;
  unsigned short* x_bf = ctx;
  float* x = (float*)alloc((size_t)NTOK * D_ * 4);                          // 8.4 MB
  float* part = (float*)alloc((size_t)2 * NTOK * FF_ * 4);                  // 67.1 MB (max KS*N)

  hipMemsetAsync(meta, 0, 256, stream);

  // --- MoE attention ---
  cast_bf16_kernel<<<1024, 256, 0, stream>>>(src, src_bf);
  gate_kernel<<<512, 256, 0, stream>>>(src, Wg_attn, idx1, gw1, cnt1);
  route_kernel<<<1, 256, 0, stream>>>(idx1, cnt1, off1, perm1, NTOK);
  gemm_kernel<2><<<dim3(3072 / 128, 8, 32), 256, 0, stream>>>(
      src_bf, 1024, Wqkv, perm1, off1, part, 1024, 3072);
  reduce_kernel<2, false, true><<<dim3(3, NTOK), 256, 0, stream>>>(
      part, bqkv, gw1, idx1, qkvb, 3072);
  vtrans_kernel<<<dim3(32, 16), 256, 0, stream>>>(qkvb, vT);
  attn_kernel<<<dim3(16, 32), 256, 0, stream>>>(qkvb, vT, kpm, ctx);
  gemm_kernel<4><<<dim3(1024 / 128, 8, 64), 256, 0, stream>>>(
      ctx, 1024, Wo, perm1, off1, part, 1024, 1024);
  ln_reduce_kernel<4, true><<<NTOK, 256, 0, stream>>>(
      src, part, bo, gw1, idx1, ln1_s, ln1_b, x, x_bf);

  // --- MoE FFN ---
  gate_kernel<<<512, 256, 0, stream>>>(x, Wg_ffn, idx2, gw2, cnt2);
  route_kernel<<<1, 256, 0, stream>>>(idx2, cnt2, off2, perm2, NTOK);
  gemm_kernel<2><<<dim3(4096 / 128, 8, 32), 256, 0, stream>>>(
      x_bf, 1024, W1, perm2, off2, part, 1024, 4096);
  reduce_kernel<2, true, true><<<dim3(4, NTOK), 256, 0, stream>>>(
      part, b1, gw2, idx2, hbuf, 4096);
  gemm_kernel<4><<<dim3(8, 8, 64), 256, 0, stream>>>(
      hbuf, 4096, W2, perm2, off2, part, 4096, 1024);
  ln_reduce_kernel<4, false><<<NTOK, 256, 0, stream>>>(
      x, part, b2, gw2, idx2, ln2_s, ln2_b, out, (unsigned short*)nullptr);
}

// Round 3
// 653.509 us; speedup vs baseline: 1.0695x; 1.0695x over previous
//
#include <hip/hip_runtime.h>

// MoE Transformer encoder layer, MI355X/gfx950.
// R6: traffic-first redesign of the grouped GEMM (it is ~10x memory-bound:
// per k-step a block must read 32KB vs ~160 cyc of MFMA).
//  - M=256, N=128, BK=32, 512 thr / 8 waves: W fp32 read EXACTLY once.
//  - KS=1 + fused bias+gate(+gelu)+bf16 epilogue for QKV and W1 GEMMs ->
//    standalone reduce kernels gone, ~300MB of fp32 partial round-trip gone.
//  - Wo/W2 keep KS=2 fp32 partials (concurrency), consumed by fused ln_reduce.
//  - Warp-specialized staging: waves 0-3 stage B with FULL-ROW 512B-contiguous
//    f32x4 geometry (DRAM-page friendly), waves 4-7 stage A (bf16, L2-hot).
//    Split threads -> independent per-thread vmcnt queues, exact counted waits.
//  - Counted-wait pipeline: B 2 k-steps ahead, A 1 ahead; raw s_barrier +
//    lgkmcnt(0) only; no vmcnt drain in the loop.

#define B_   2
#define N_   1024
#define D_   1024
#define H_   16
#define DH_  64
#define FF_  4096
#define E_   8
#define NTOK 2048

typedef __attribute__((ext_vector_type(8))) short short8;
typedef __attribute__((ext_vector_type(8))) unsigned short ushort8;
typedef __attribute__((ext_vector_type(4))) unsigned short ushort4v;
typedef __attribute__((ext_vector_type(4))) float f32x4;
typedef __attribute__((ext_vector_type(2))) unsigned int uint32x2;

__device__ inline unsigned short f2bf(float f) {
  unsigned u = __float_as_uint(f);
  u += 0x7FFFu + ((u >> 16) & 1u);   // round-to-nearest-even
  return (unsigned short)(u >> 16);
}

__device__ inline float gelu_tanh(float x) {
  float x3 = x * x * x;
  float t = tanhf(0.7978845608028654f * (x + 0.044715f * x3));
  return 0.5f * x * (1.0f + t);
}

// ---------------- gating: one wave per token, fp32 exact ----------------
__global__ __launch_bounds__(256) void gate_kernel(
    const float* __restrict__ X, const float* __restrict__ Wg,
    int* __restrict__ idx, float* __restrict__ gwv, int* __restrict__ cnt) {
  int t = blockIdx.x * 4 + (threadIdx.x >> 6);
  int lane = threadIdx.x & 63;
  const float* x = X + (size_t)t * D_;
  float acc[E_];
#pragma unroll
  for (int j = 0; j < E_; j++) acc[j] = 0.f;
#pragma unroll
  for (int i = 0; i < 16; i++) {
    int d = i * 64 + lane;
    float xv = x[d];
    const float4* w = (const float4*)(Wg + (size_t)d * E_);
    float4 w0 = w[0], w1 = w[1];
    acc[0] += xv * w0.x; acc[1] += xv * w0.y; acc[2] += xv * w0.z; acc[3] += xv * w0.w;
    acc[4] += xv * w1.x; acc[5] += xv * w1.y; acc[6] += xv * w1.z; acc[7] += xv * w1.w;
  }
#pragma unroll
  for (int o = 1; o < 64; o <<= 1) {
#pragma unroll
    for (int j = 0; j < E_; j++) acc[j] += __shfl_xor(acc[j], o, 64);
  }
  float m = acc[0]; int bi = 0;
#pragma unroll
  for (int j = 1; j < E_; j++) { if (acc[j] > m) { m = acc[j]; bi = j; } }
  float den = 0.f;
#pragma unroll
  for (int j = 0; j < E_; j++) den += expf(acc[j] - m);
  float gw = expf(acc[bi] - m) / den;
  if (lane == 0) { idx[t] = bi; gwv[t] = gw; atomicAdd(&cnt[bi], 1); }
}

// ---------------- routing: single block builds per-expert lists ----------------
__global__ __launch_bounds__(256) void route_kernel(
    const int* __restrict__ idx, const int* __restrict__ cnt,
    int* __restrict__ off, int* __restrict__ perm, int ntok) {
  __shared__ int loff[E_ + 1];
  __shared__ int lfill[E_];
  if (threadIdx.x == 0) {
    int s = 0;
    for (int e = 0; e < E_; e++) { loff[e] = s; s += cnt[e]; }
    loff[E_] = s;
  }
  if (threadIdx.x < E_) lfill[threadIdx.x] = 0;
  __syncthreads();
  for (int t = (int)threadIdx.x; t < ntok; t += 256) {
    int e = idx[t];
    int p = atomicAdd(&lfill[e], 1);
    perm[loff[e] + p] = t;
  }
  if (threadIdx.x < E_ + 1) off[threadIdx.x] = loff[threadIdx.x];
}

// ---------------- fp32 -> bf16 bulk cast ----------------
__global__ __launch_bounds__(256) void cast_bf16_kernel(
    const float* __restrict__ in, unsigned short* __restrict__ out) {
  size_t i = ((size_t)blockIdx.x * 256 + threadIdx.x) * 8;
  float4 v0 = *(const float4*)(in + i);
  float4 v1 = *(const float4*)(in + i + 4);
  ushort8 o;
  o[0] = f2bf(v0.x); o[1] = f2bf(v0.y); o[2] = f2bf(v0.z); o[3] = f2bf(v0.w);
  o[4] = f2bf(v1.x); o[5] = f2bf(v1.y); o[6] = f2bf(v1.z); o[7] = f2bf(v1.w);
  *(ushort8*)(out + i) = o;
}

// ---------------- grouped MoE GEMM, warp-specialized staging ----------------
// out = A[toks]·W[e] (+bias, *gw, gelu) over K-chunk kc.
// Tiles: M=256, N=128, BK=32. 512 thr = 8 waves (4m x 2n), wave = 64x64.
// Waves 0-3 (tid<256) stage B: thread (c=tid&31, rq=tid>>5) reads 4 k-rows
//   (k4=rq*4) x f32x4 at n0=c*4 -> each load instr covers 512B-contiguous
//   row segments (DRAM-friendly). Cast+transpose+swizzle into Bs.
// Waves 4-7 stage A: thread arow=tid&255 reads its token row's 64B.
// Pipeline: publish(t); issue A(t+1), B(t+2); lgkmcnt(0); barrier;
//   MFMA(t); barrier.  vmcnt waits are compiler-counted per split queue.
// EPI: 0 = fp32 partials (split-K);  1 = bf16 (acc+bias)*gw;  2 = +gelu.
template <int KS, int EPI>
__global__ __launch_bounds__(512, 2) void gemm_kernel(
    const unsigned short* __restrict__ A, int ldA,
    const float* __restrict__ W,
    const float* __restrict__ bias, const float* __restrict__ gwv,
    const int* __restrict__ perm, const int* __restrict__ off,
    void* __restrict__ outp, int K, int N) {
  __shared__ __align__(16) unsigned short As[256][32];
  __shared__ __align__(16) unsigned short Bs[128][40];
  __shared__ int toks[256];
  __shared__ float gws[256];

  int e = blockIdx.y;
  int base = off[e];
  int cnt = off[e + 1] - base;
  int mt = blockIdx.z / KS;
  int kc = blockIdx.z % KS;
  int m0 = mt * 256;
  if (m0 >= cnt) return;
  int rows_valid = min(256, cnt - m0);
  int tid = threadIdx.x;
  if (tid < 256) {
    int r = (tid < rows_valid) ? tid : (rows_valid - 1);
    int tk = perm[base + m0 + r];
    toks[tid] = tk;
    gws[tid] = gwv[tk];
  }
  int nb = blockIdx.x * 128;
  int lane = tid & 63, wave = tid >> 6;
  int wm = (wave & 3) * 64, wn = (wave >> 2) * 64;
  int lr = lane & 15, lg = lane >> 4;
  int aswz = (lg ^ ((lr >> 1) & 3)) << 3;
  int bswz = (lg ^ ((lr >> 2) & 3)) << 3;

  f32x4 acc[4][4];
#pragma unroll
  for (int m = 0; m < 4; m++)
#pragma unroll
    for (int n = 0; n < 4; n++) acc[m][n] = (f32x4){0.f, 0.f, 0.f, 0.f};

  // staging geometry
  bool isB = tid < 256;
  int c = tid & 31, rq = (tid >> 5) & 7;
  int k4 = rq * 4, n0 = c * 4;
  int arow = tid & 255;
  int as_ = (arow >> 1) & 3;

  int KL = K / KS, kbeg = kc * KL;
  int nt = KL / 32;
  __syncthreads();   // toks/gws visible

  const unsigned short* abase = A + (size_t)toks[arow] * ldA;
  const float* wbase = W + ((size_t)e * K + k4) * N + nb + n0;

  ushort8 aR0, aR1, aR2, aR3;
  f32x4 bA0, bA1, bA2, bA3, bB0, bB1, bB2, bB3;

#define LOAD_A(KK) if (!isB) {                                            \
    const unsigned short* ap = abase + (KK);                              \
    aR0 = *(const ushort8*)ap;                                            \
    aR1 = *(const ushort8*)(ap + 8);                                      \
    aR2 = *(const ushort8*)(ap + 16);                                     \
    aR3 = *(const ushort8*)(ap + 24); }

#define LOAD_B(KK, R0, R1, R2, R3) if (isB) {                             \
    const float* wp = wbase + (size_t)(KK) * N;                           \
    R0 = *(const f32x4*)wp;                                               \
    R1 = *(const f32x4*)(wp + N);                                         \
    R2 = *(const f32x4*)(wp + 2 * N);                                     \
    R3 = *(const f32x4*)(wp + 3 * N); }

#define PUBLISH(R0, R1, R2, R3) {                                         \
    if (isB) {                                                            \
      _Pragma("unroll")                                                   \
      for (int j = 0; j < 4; j++) {                                       \
        int n = n0 + j;                                                   \
        int bb = (((k4 >> 3) ^ ((n >> 2) & 3)) << 3) | (k4 & 7);          \
        unsigned lo = (unsigned)f2bf(R0[j]) | ((unsigned)f2bf(R1[j]) << 16);\
        unsigned hi = (unsigned)f2bf(R2[j]) | ((unsigned)f2bf(R3[j]) << 16);\
        *(uint32x2*)&Bs[n][bb] = (uint32x2){lo, hi};                      \
      }                                                                   \
    } else {                                                              \
      *(ushort8*)&As[arow][(0 ^ as_) << 3] = aR0;                         \
      *(ushort8*)&As[arow][(1 ^ as_) << 3] = aR1;                         \
      *(ushort8*)&As[arow][(2 ^ as_) << 3] = aR2;                         \
      *(ushort8*)&As[arow][(3 ^ as_) << 3] = aR3;                         \
    } }

#define COMPUTE() {                                                       \
    short8 av[4], bv[4];                                                  \
    _Pragma("unroll")                                                     \
    for (int m = 0; m < 4; m++)                                           \
      av[m] = *(const short8*)&As[wm + m * 16 + lr][aswz];                \
    _Pragma("unroll")                                                     \
    for (int n = 0; n < 4; n++)                                           \
      bv[n] = *(const short8*)&Bs[wn + n * 16 + lr][bswz];                \
    __builtin_amdgcn_s_setprio(1);                                        \
    _Pragma("unroll")                                                     \
    for (int n = 0; n < 4; n++)                                           \
      _Pragma("unroll")                                                   \
      for (int m = 0; m < 4; m++)                                         \
        acc[m][n] = __builtin_amdgcn_mfma_f32_16x16x32_bf16(              \
            av[m], bv[n], acc[m][n], 0, 0, 0);                            \
    __builtin_amdgcn_s_setprio(0); }

  // prologue: A(0), B(0), B(1)
  LOAD_A(kbeg);
  LOAD_B(kbeg, bA0, bA1, bA2, bA3);
  if (nt > 1) LOAD_B(kbeg + 32, bB0, bB1, bB2, bB3);

  for (int t = 0; t < nt; t += 2) {
    int k0 = kbeg + t * 32;
    // ---- even step t ----
    PUBLISH(bA0, bA1, bA2, bA3);
    if (t + 1 < nt) LOAD_A(k0 + 32);
    if (t + 2 < nt) LOAD_B(k0 + 64, bA0, bA1, bA2, bA3);
    asm volatile("s_waitcnt lgkmcnt(0)" ::: "memory");
    __builtin_amdgcn_s_barrier();
    COMPUTE();
    __builtin_amdgcn_s_barrier();
    // ---- odd step t+1 ----
    if (t + 1 < nt) {
      PUBLISH(bB0, bB1, bB2, bB3);
      if (t + 2 < nt) LOAD_A(k0 + 64);
      if (t + 3 < nt) LOAD_B(k0 + 96, bB0, bB1, bB2, bB3);
      asm volatile("s_waitcnt lgkmcnt(0)" ::: "memory");
      __builtin_amdgcn_s_barrier();
      COMPUTE();
      __builtin_amdgcn_s_barrier();
    }
  }
#undef LOAD_A
#undef LOAD_B
#undef PUBLISH
#undef COMPUTE

  if constexpr (EPI == 0) {
    float* pr = (float*)outp + (size_t)kc * ((size_t)NTOK * N);
#pragma unroll
    for (int n = 0; n < 4; n++) {
      int col = nb + wn + n * 16 + lr;
#pragma unroll
      for (int m = 0; m < 4; m++) {
#pragma unroll
        for (int reg = 0; reg < 4; reg++) {
          int r = wm + m * 16 + lg * 4 + reg;
          if (r < rows_valid)
            pr[(size_t)toks[r] * N + col] = acc[m][n][reg];
        }
      }
    }
  } else {
    unsigned short* po = (unsigned short*)outp;
    float bcol[4];
#pragma unroll
    for (int n = 0; n < 4; n++)
      bcol[n] = bias[(size_t)e * N + nb + wn + n * 16 + lr];
#pragma unroll
    for (int n = 0; n < 4; n++) {
      int col = nb + wn + n * 16 + lr;
#pragma unroll
      for (int m = 0; m < 4; m++) {
#pragma unroll
        for (int reg = 0; reg < 4; reg++) {
          int r = wm + m * 16 + lg * 4 + reg;
          if (r < rows_valid) {
            float v = (acc[m][n][reg] + bcol[n]) * gws[r];
            if constexpr (EPI == 2) v = gelu_tanh(v);
            po[(size_t)toks[r] * N + col] = f2bf(v);
          }
        }
      }
    }
  }
}

// ---------------- V transpose per (b,h) ----------------
__global__ __launch_bounds__(256) void vtrans_kernel(
    const unsigned short* __restrict__ qkv, unsigned short* __restrict__ vT) {
  __shared__ __align__(16) unsigned short T[64][72];
  int bh = blockIdx.x;
  int b = bh >> 4, h = bh & 15;
  int tile = blockIdx.y;
  int tid = threadIdx.x;
  {
    int tk = tid >> 2, dof = (tid & 3) * 16;
    const unsigned short* p =
        qkv + ((size_t)(b * N_ + tile * 64 + tk)) * 3072 + 2048 + h * 64 + dof;
    *(ushort8*)&T[tk][dof] = *(const ushort8*)p;
    *(ushort8*)&T[tk][dof + 8] = *(const ushort8*)(p + 8);
  }
  __syncthreads();
  {
    int dh = tid >> 2, tof = (tid & 3) * 16;
    ushort8 o0, o1;
#pragma unroll
    for (int i = 0; i < 8; i++) o0[i] = T[tof + i][dh];
#pragma unroll
    for (int i = 0; i < 8; i++) o1[i] = T[tof + 8 + i][dh];
    unsigned short* q = vT + ((size_t)bh * 64 + dh) * N_ + tile * 64 + tof;
    *(ushort8*)q = o0;
    *(ushort8*)(q + 8) = o1;
  }
}

// ---------------- flash attention ----------------
__global__ __launch_bounds__(256) void attn_kernel(
    const unsigned short* __restrict__ qkv, const unsigned short* __restrict__ vT,
    const unsigned char* __restrict__ kpm, unsigned short* __restrict__ ctx) {
  __shared__ __align__(16) unsigned short Qs[64][72];
  __shared__ __align__(16) unsigned short Ks[64][72];
  __shared__ __align__(16) unsigned short Vs[64][72];
  __shared__ __align__(16) unsigned short Ps[4][16][72];
  __shared__ float maskf[64];
  int qt = blockIdx.x, bh = blockIdx.y;
  int b = bh >> 4, h = bh & 15;
  int tid = threadIdx.x, lane = tid & 63, wave = tid >> 6;
  int lr = lane & 15, lg = lane >> 4;
  {
    int r = tid >> 2, dof = (tid & 3) * 16;
    const unsigned short* p = qkv + ((size_t)(b * N_ + qt * 64 + r)) * 3072 + h * 64 + dof;
    *(ushort8*)&Qs[r][dof] = *(const ushort8*)p;
    *(ushort8*)&Qs[r][dof + 8] = *(const ushort8*)(p + 8);
  }
  __syncthreads();
  short8 aq[2];
  aq[0] = *(const short8*)&Qs[wave * 16 + lr][lg * 8];
  aq[1] = *(const short8*)&Qs[wave * 16 + lr][32 + lg * 8];
  f32x4 O[4];
  float mrun[4], lrun[4];
#pragma unroll
  for (int r = 0; r < 4; r++) { mrun[r] = -1e30f; lrun[r] = 0.f; O[r] = (f32x4){0.f, 0.f, 0.f, 0.f}; }

  for (int kt = 0; kt < 16; kt++) {
    __syncthreads();
    {
      int r = tid >> 2, dof = (tid & 3) * 16;
      const unsigned short* p =
          qkv + ((size_t)(b * N_ + kt * 64 + r)) * 3072 + 1024 + h * 64 + dof;
      *(ushort8*)&Ks[r][dof] = *(const ushort8*)p;
      *(ushort8*)&Ks[r][dof + 8] = *(const ushort8*)(p + 8);
      const unsigned short* pv = vT + ((size_t)bh * 64 + r) * N_ + kt * 64 + dof;
      *(ushort8*)&Vs[r][dof] = *(const ushort8*)pv;
      *(ushort8*)&Vs[r][dof + 8] = *(const ushort8*)(pv + 8);
      if (tid < 64) maskf[tid] = kpm[b * N_ + kt * 64 + tid] ? -10000.f : 0.f;
    }
    __syncthreads();
    f32x4 S[4];
#pragma unroll
    for (int n = 0; n < 4; n++) {
      f32x4 s = (f32x4){0.f, 0.f, 0.f, 0.f};
#pragma unroll
      for (int ks = 0; ks < 2; ks++) {
        short8 bk = *(const short8*)&Ks[n * 16 + lr][ks * 32 + lg * 8];
        s = __builtin_amdgcn_mfma_f32_16x16x32_bf16(aq[ks], bk, s, 0, 0, 0);
      }
      float mv = maskf[n * 16 + lr];
#pragma unroll
      for (int r = 0; r < 4; r++) s[r] = s[r] * 0.125f + mv;
      S[n] = s;
    }
    float cur[4];
#pragma unroll
    for (int r = 0; r < 4; r++)
      cur[r] = fmaxf(fmaxf(S[0][r], S[1][r]), fmaxf(S[2][r], S[3][r]));
#pragma unroll
    for (int o = 1; o < 16; o <<= 1) {
#pragma unroll
      for (int r = 0; r < 4; r++) cur[r] = fmaxf(cur[r], __shfl_xor(cur[r], o, 64));
    }
    float alpha[4], rsum[4];
#pragma unroll
    for (int r = 0; r < 4; r++) {
      float mn = fmaxf(mrun[r], cur[r]);
      alpha[r] = expf(mrun[r] - mn);
      mrun[r] = mn;
      rsum[r] = 0.f;
    }
#pragma unroll
    for (int n = 0; n < 4; n++) {
#pragma unroll
      for (int r = 0; r < 4; r++) {
        S[n][r] = expf(S[n][r] - mrun[r]);
        rsum[r] += S[n][r];
      }
    }
#pragma unroll
    for (int o = 1; o < 16; o <<= 1) {
#pragma unroll
      for (int r = 0; r < 4; r++) rsum[r] += __shfl_xor(rsum[r], o, 64);
    }
#pragma unroll
    for (int r = 0; r < 4; r++) lrun[r] = lrun[r] * alpha[r] + rsum[r];
#pragma unroll
    for (int d = 0; d < 4; d++)
#pragma unroll
      for (int r = 0; r < 4; r++) O[d][r] *= alpha[r];
#pragma unroll
    for (int n = 0; n < 4; n++)
#pragma unroll
      for (int r = 0; r < 4; r++) Ps[wave][lg * 4 + r][n * 16 + lr] = f2bf(S[n][r]);
    short8 pf[2];
    pf[0] = *(const short8*)&Ps[wave][lr][lg * 8];
    pf[1] = *(const short8*)&Ps[wave][lr][32 + lg * 8];
#pragma unroll
    for (int d = 0; d < 4; d++) {
#pragma unroll
      for (int ks = 0; ks < 2; ks++) {
        short8 bv = *(const short8*)&Vs[d * 16 + lr][ks * 32 + lg * 8];
        O[d] = __builtin_amdgcn_mfma_f32_16x16x32_bf16(pf[ks], bv, O[d], 0, 0, 0);
      }
    }
  }
#pragma unroll
  for (int r = 0; r < 4; r++) lrun[r] = 1.f / lrun[r];
#pragma unroll
  for (int d = 0; d < 4; d++) {
#pragma unroll
    for (int r = 0; r < 4; r++) {
      int q = qt * 64 + wave * 16 + lg * 4 + r;
      int dh = d * 16 + lr;
      ctx[((size_t)(b * N_ + q)) * D_ + h * DH_ + dh] = f2bf(O[d][r] * lrun[r]);
    }
  }
}

// ---------------- fused: out = LN(res + (Σ part + bias)·gw) [+bf16 copy] ----------------
template <int KS, bool WBF>
__global__ __launch_bounds__(256) void ln_reduce_kernel(
    const float* __restrict__ res, const float* __restrict__ part,
    const float* __restrict__ bias, const float* __restrict__ gwv,
    const int* __restrict__ idx,
    const float* __restrict__ S, const float* __restrict__ Bi,
    float* __restrict__ O, unsigned short* __restrict__ Obf) {
  int t = blockIdx.x, tid = threadIdx.x;
  int e = idx[t];
  float gw = gwv[t];
  const float* p = part + (size_t)t * D_ + tid * 4;
  float4 a = *(const float4*)p;
#pragma unroll
  for (int k = 1; k < KS; k++) {
    float4 q = *(const float4*)(p + (size_t)k * NTOK * D_);
    a.x += q.x; a.y += q.y; a.z += q.z; a.w += q.w;
  }
  float4 bv4 = *(const float4*)(bias + (size_t)e * D_ + tid * 4);
  float4 vr = ((const float4*)(res + (size_t)t * D_))[tid];
  float4 v;
  v.x = vr.x + (a.x + bv4.x) * gw;
  v.y = vr.y + (a.y + bv4.y) * gw;
  v.z = vr.z + (a.z + bv4.z) * gw;
  v.w = vr.w + (a.w + bv4.w) * gw;
  float s = v.x + v.y + v.z + v.w;
  float sq = v.x * v.x + v.y * v.y + v.z * v.z + v.w * v.w;
#pragma unroll
  for (int o = 1; o < 64; o <<= 1) {
    s += __shfl_xor(s, o, 64);
    sq += __shfl_xor(sq, o, 64);
  }
  __shared__ float ss[4], ssq[4];
  int wave = tid >> 6, lane = tid & 63;
  if (lane == 0) { ss[wave] = s; ssq[wave] = sq; }
  __syncthreads();
  float ts = ss[0] + ss[1] + ss[2] + ss[3];
  float tsq = ssq[0] + ssq[1] + ssq[2] + ssq[3];
  float mean = ts * (1.f / D_);
  float var = tsq * (1.f / D_) - mean * mean;
  float rs = rsqrtf(var + 1e-5f);
  float4 sv = ((const float4*)S)[tid];
  float4 bi = ((const float4*)Bi)[tid];
  float4 o;
  o.x = (v.x - mean) * rs * sv.x + bi.x;
  o.y = (v.y - mean) * rs * sv.y + bi.y;
  o.z = (v.z - mean) * rs * sv.z + bi.z;
  o.w = (v.w - mean) * rs * sv.w + bi.w;
  ((float4*)(O + (size_t)t * D_))[tid] = o;
  if constexpr (WBF) {
    ushort4v ob;
    ob[0] = f2bf(o.x); ob[1] = f2bf(o.y); ob[2] = f2bf(o.z); ob[3] = f2bf(o.w);
    *(ushort4v*)(Obf + (size_t)t * D_ + tid * 4) = ob;
  }
}

extern "C" void kernel_launch(void* const* d_in, const int* in_sizes, int n_in,
                              void* d_out, int out_size, void* d_ws, size_t ws_size,
                              hipStream_t stream) {
  (void)in_sizes; (void)n_in; (void)out_size; (void)ws_size;
  const float* src     = (const float*)d_in[0];
  const unsigned char* kpm = (const unsigned char*)d_in[1];
  const float* Wg_attn = (const float*)d_in[2];
  const float* Wqkv    = (const float*)d_in[3];
  const float* bqkv    = (const float*)d_in[4];
  const float* Wo      = (const float*)d_in[5];
  const float* bo      = (const float*)d_in[6];
  const float* Wg_ffn  = (const float*)d_in[7];
  const float* W1      = (const float*)d_in[8];
  const float* b1      = (const float*)d_in[9];
  const float* W2      = (const float*)d_in[10];
  const float* b2      = (const float*)d_in[11];
  const float* ln1_s   = (const float*)d_in[12];
  const float* ln1_b   = (const float*)d_in[13];
  const float* ln2_s   = (const float*)d_in[14];
  const float* ln2_b   = (const float*)d_in[15];
  float* out = (float*)d_out;

  char* ws = (char*)d_ws;
  size_t o = 0;
  auto alloc = [&](size_t bytes) -> void* {
    void* p = ws + o;
    o += (bytes + 255) & ~(size_t)255;
    return p;
  };
  int* meta = (int*)alloc(256);
  int* cnt1 = meta;
  int* off1 = meta + 8;
  int* cnt2 = meta + 17;
  int* off2 = meta + 25;
  int* idx1 = (int*)alloc(NTOK * 4);
  float* gw1 = (float*)alloc(NTOK * 4);
  int* perm1 = (int*)alloc(NTOK * 4);
  int* idx2 = (int*)alloc(NTOK * 4);
  float* gw2 = (float*)alloc(NTOK * 4);
  int* perm2 = (int*)alloc(NTOK * 4);
  unsigned short* qkvb = (unsigned short*)alloc((size_t)NTOK * 3072 * 2);   // 12.6 MB
  unsigned short* vT = (unsigned short*)alloc((size_t)32 * 64 * N_ * 2);    // 4.2 MB
  unsigned short* hbuf = qkvb;  // h[2048][4096] bf16 reuses qkv+vT (16.78 MB)
  unsigned short* ctx = (unsigned short*)alloc((size_t)NTOK * D_ * 2);      // 4.2 MB
  // ctx buffer triple-duty (all lifetimes disjoint on the stream):
  //   [cast .. QKV gemm]      src_bf (bf16 src)
  //   [attn .. Wo gemm]       ctx (attention output)
  //   [ln_reduce1 .. W1 gemm] x_bf (bf16 x)
  unsigned short* src_bf = ctx;
  unsigned short* x_bf = ctx;
  float* x = (float*)alloc((size_t)NTOK * D_ * 4);                          // 8.4 MB
  float* part = (float*)alloc((size_t)2 * NTOK * D_ * 4);                   // 16.8 MB (KS=2, N=1024)

  hipMemsetAsync(meta, 0, 256, stream);

  // --- MoE attention ---
  cast_bf16_kernel<<<1024, 256, 0, stream>>>(src, src_bf);
  gate_kernel<<<512, 256, 0, stream>>>(src, Wg_attn, idx1, gw1, cnt1);
  route_kernel<<<1, 256, 0, stream>>>(idx1, cnt1, off1, perm1, NTOK);
  // QKV: KS=1, fused bias+gate -> qkvb bf16
  gemm_kernel<1, 1><<<dim3(3072 / 128, 8, 8), 512, 0, stream>>>(
      src_bf, 1024, Wqkv, bqkv, gw1, perm1, off1, qkvb, 1024, 3072);
  vtrans_kernel<<<dim3(32, 16), 256, 0, stream>>>(qkvb, vT);
  attn_kernel<<<dim3(16, 32), 256, 0, stream>>>(qkvb, vT, kpm, ctx);
  // Wo: KS=2, fp32 partials -> ln_reduce
  gemm_kernel<2, 0><<<dim3(1024 / 128, 8, 16), 512, 0, stream>>>(
      ctx, 1024, Wo, bo, gw1, perm1, off1, part, 1024, 1024);
  ln_reduce_kernel<2, true><<<NTOK, 256, 0, stream>>>(
      src, part, bo, gw1, idx1, ln1_s, ln1_b, x, x_bf);

  // --- MoE FFN ---
  gate_kernel<<<512, 256, 0, stream>>>(x, Wg_ffn, idx2, gw2, cnt2);
  route_kernel<<<1, 256, 0, stream>>>(idx2, cnt2, off2, perm2, NTOK);
  // W1: KS=1, fused bias+gate+gelu -> hbuf bf16
  gemm_kernel<1, 2><<<dim3(4096 / 128, 8, 8), 512, 0, stream>>>(
      x_bf, 1024, W1, b1, gw2, perm2, off2, hbuf, 1024, 4096);
  // W2: KS=2, fp32 partials -> ln_reduce
  gemm_kernel<2, 0><<<dim3(1024 / 128, 8, 16), 512, 0, stream>>>(
      hbuf, 4096, W2, b2, gw2, perm2, off2, part, 4096, 1024);
  ln_reduce_kernel<2, false><<<NTOK, 256, 0, stream>>>(
      x, part, b2, gw2, idx2, ln2_s, ln2_b, out, (unsigned short*)nullptr);
}